// Round 3
// baseline (585.802 us; speedup 1.0000x reference)
//
#include <hip/hip_runtime.h>

// XCA: cross-covariance attention, B=32 N=3136 D=384 H=8 C=48.
// Round 3: XCD-aware block swizzle on both big GEMMs (keep tile reuse within
// one XCD's L2); attn_s atomics replaced by split-K partial stores
// (S_part[7][bh][48][48], ssq_part[7][2][bh][48]) reduced inside softmax.

typedef __bf16 bf16x8 __attribute__((ext_vector_type(8)));
typedef float floatx4 __attribute__((ext_vector_type(4)));
typedef unsigned short u16;

#define B_ 32
#define N_ 3136
#define D_ 384
#define H_ 8
#define C_ 48
#define E3_ 1152
#define BN_ 100352   // B_*N_

__device__ __forceinline__ u16 f2b(float f) {
  unsigned u = __builtin_bit_cast(unsigned, f);
  u += 0x7FFFu + ((u >> 16) & 1u);   // RNE
  return (u16)(u >> 16);
}
__device__ __forceinline__ float b2f(u16 s) {
  unsigned u = ((unsigned)s) << 16;
  return __builtin_bit_cast(float, u);
}
__device__ __forceinline__ void gload16(const u16* g, u16* l) {
  __builtin_amdgcn_global_load_lds(
      (const __attribute__((address_space(1))) void*)g,
      (__attribute__((address_space(3))) void*)l, 16, 0, 0);
}

// ---------------- fp32 -> bf16 convert ----------------
__global__ __launch_bounds__(256) void k_cvt(const float* __restrict__ in,
                                             u16* __restrict__ out, int n4) {
  int i = blockIdx.x * 256 + threadIdx.x;
  if (i < n4) {
    float4 v = ((const float4*)in)[i];
    ushort4 o;
    o.x = f2b(v.x); o.y = f2b(v.y); o.z = f2b(v.z); o.w = f2b(v.w);
    ((ushort4*)out)[i] = o;
  }
}

// ---------------- GEMM1: O[e][g] = sum_d W[e][d] X[g][d], bf16 out ----------
// m97 structure, 1-D grid of 7056 with XCD swizzle: each XCD gets 98 complete
// g-tile groups (9 e-tiles each) so the X-tile stays in that XCD's L2.
__global__ __launch_bounds__(256) void k_gemm_qkv(const u16* __restrict__ W,
                                                  const u16* __restrict__ X,
                                                  u16* __restrict__ O) {
  const int K = D_;
  int id = blockIdx.x;
  int work = (id & 7) * 882 + (id >> 3);   // 7056 = 8 XCD * 882
  int m0 = (work % 9) * 128;               // e
  int n0 = (work / 9) * 128;               // g
  __shared__ u16 As[128][32];
  __shared__ u16 Bs[128][32];
  int t = threadIdx.x, wid = t >> 6, lane = t & 63;
  int srow = wid * 32 + (lane >> 2);
  int scol = (lane & 3) * 8;
  int wm = (wid & 1) * 64, wn = (wid >> 1) * 64;
  int r = lane & 15, quad = lane >> 4, q8 = quad * 8;

  const u16* gA = W + (size_t)(m0 + srow) * K + scol;
  const u16* gB = X + (size_t)(n0 + srow) * K + scol;
  u16* lA0 = &As[wid * 32][0];
  u16* lA1 = &As[wid * 32 + 16][0];
  u16* lB0 = &Bs[wid * 32][0];
  u16* lB1 = &Bs[wid * 32 + 16][0];

  floatx4 acc[4][4] = {};
  for (int k0 = 0; k0 < K; k0 += 32) {
    gload16(gA + k0, lA0);
    gload16(gA + k0 + 16 * K, lA1);
    gload16(gB + k0, lB0);
    gload16(gB + k0 + 16 * K, lB1);
    __syncthreads();
    bf16x8 af[4], bf[4];
    for (int i = 0; i < 4; i++) af[i] = *(const bf16x8*)(&As[wm + i * 16 + r][q8]);
    for (int j = 0; j < 4; j++) bf[j] = *(const bf16x8*)(&Bs[wn + j * 16 + r][q8]);
    for (int i = 0; i < 4; i++)
      for (int j = 0; j < 4; j++)
        acc[i][j] = __builtin_amdgcn_mfma_f32_16x16x32_bf16(af[i], bf[j], acc[i][j], 0, 0, 0);
    __syncthreads();
  }
  for (int i = 0; i < 4; i++)
    for (int j = 0; j < 4; j++)
      for (int v = 0; v < 4; v++) {
        int rr = m0 + wm + i * 16 + quad * 4 + v;
        int cc = n0 + wn + j * 16 + r;
        O[(size_t)rr * BN_ + cc] = f2b(acc[i][j][v]);
      }
}

// ---------------- attn_s: split-K partial tiles + fused sumsq ---------------
// S_part[split][bh][c][d] = Q_bh[c][ns..] . K_bh[d][..]^T  (plain stores)
// grid: x = bh(256), y = split(7). 64x64 padded tile, 4 waves.
__global__ __launch_bounds__(256) void k_attn_s(const u16* __restrict__ QKV,
                                                float* __restrict__ S_part,
                                                float* __restrict__ ssq_part) {
  int bh = blockIdx.x, b = bh >> 3, h = bh & 7;
  int split = blockIdx.y;
  int ns = split * 448;
  const u16* Qb = QKV + (size_t)(h * C_) * BN_ + b * N_ + ns;
  const u16* Kb = QKV + (size_t)(D_ + h * C_) * BN_ + b * N_ + ns;
  __shared__ u16 As[64][32];
  __shared__ u16 Bs[64][32];
  int t = threadIdx.x;
  int row = t >> 2, chunk = (t & 3) * 8;
  int wid = t >> 6, lane = t & 63;
  int wm = (wid & 1) * 32, wn = (wid >> 1) * 32;
  int r = lane & 15, quad = lane >> 4, q8 = quad * 8;
  float sq_acc = 0.f, sk_acc = 0.f;
  floatx4 acc[2][2] = {};
  for (int k0 = 0; k0 < 448; k0 += 32) {
    int4 va = {0, 0, 0, 0}, vb = {0, 0, 0, 0};
    if (row < 48) {
      va = *(const int4*)(Qb + (size_t)row * BN_ + k0 + chunk);
      vb = *(const int4*)(Kb + (size_t)row * BN_ + k0 + chunk);
    }
    *(int4*)(&As[row][chunk]) = va;
    *(int4*)(&Bs[row][chunk]) = vb;
    const u16* pa = (const u16*)&va;
    const u16* pb = (const u16*)&vb;
    for (int i = 0; i < 8; i++) {
      float fa = b2f(pa[i]), fb = b2f(pb[i]);
      sq_acc += fa * fa; sk_acc += fb * fb;
    }
    __syncthreads();
    bf16x8 a0 = *(const bf16x8*)(&As[wm + r][q8]);
    bf16x8 a1 = *(const bf16x8*)(&As[wm + 16 + r][q8]);
    bf16x8 b0 = *(const bf16x8*)(&Bs[wn + r][q8]);
    bf16x8 b1 = *(const bf16x8*)(&Bs[wn + 16 + r][q8]);
    acc[0][0] = __builtin_amdgcn_mfma_f32_16x16x32_bf16(a0, b0, acc[0][0], 0, 0, 0);
    acc[0][1] = __builtin_amdgcn_mfma_f32_16x16x32_bf16(a0, b1, acc[0][1], 0, 0, 0);
    acc[1][0] = __builtin_amdgcn_mfma_f32_16x16x32_bf16(a1, b0, acc[1][0], 0, 0, 0);
    acc[1][1] = __builtin_amdgcn_mfma_f32_16x16x32_bf16(a1, b1, acc[1][1], 0, 0, 0);
    __syncthreads();
  }
  // sumsq: 4 threads per row
  sq_acc += __shfl_xor(sq_acc, 1); sq_acc += __shfl_xor(sq_acc, 2);
  sk_acc += __shfl_xor(sk_acc, 1); sk_acc += __shfl_xor(sk_acc, 2);
  if ((t & 3) == 0 && row < 48) {
    ssq_part[(((size_t)split * 2 + 0) * 256 + bh) * 48 + row] = sq_acc;
    ssq_part[(((size_t)split * 2 + 1) * 256 + bh) * 48 + row] = sk_acc;
  }
  float* Sp = S_part + ((size_t)split * 256 + bh) * 2304;
  for (int mt = 0; mt < 2; mt++)
    for (int nt = 0; nt < 2; nt++)
      for (int v = 0; v < 4; v++) {
        int rr = wm + mt * 16 + quad * 4 + v;
        int cc = wn + nt * 16 + r;
        if (rr < 48 && cc < 48) Sp[rr * 48 + cc] = acc[mt][nt][v];
      }
}

// ---------------- softmax: reduce 7 partials, norm-scales, temperature ------
__global__ __launch_bounds__(64) void k_softmax(const float* __restrict__ S_part,
                                                const float* __restrict__ ssq_part,
                                                const float* __restrict__ temp,
                                                float* __restrict__ attn) {
  int bh = blockIdx.x, h = bh & 7;
  int c = threadIdx.x;
  __shared__ float skin[48];
  float sqin = 0.f;
  if (c < 48) {
    float sq = 0.f, sk = 0.f;
    for (int s = 0; s < 7; s++) {
      sq += ssq_part[(((size_t)s * 2 + 0) * 256 + bh) * 48 + c];
      sk += ssq_part[(((size_t)s * 2 + 1) * 256 + bh) * 48 + c];
    }
    sqin = 1.f / fmaxf(sqrtf(sq), 1e-12f);
    skin[c] = 1.f / fmaxf(sqrtf(sk), 1e-12f);
  }
  __syncthreads();
  if (c >= 48) return;
  float T = temp[h];
  float v[48] = {};
  for (int s = 0; s < 7; s++) {
    const float* Srow = S_part + ((size_t)s * 256 + bh) * 2304 + c * 48;
    for (int d = 0; d < 48; d++) v[d] += Srow[d];
  }
  float mx = -1e30f;
  for (int d = 0; d < 48; d++) {
    v[d] = v[d] * sqin * skin[d] * T;
    mx = fmaxf(mx, v[d]);
  }
  float sum = 0.f;
  for (int d = 0; d < 48; d++) { v[d] = expf(v[d] - mx); sum += v[d]; }
  float inv = 1.f / sum;
  float* Arow = attn + (size_t)bh * 2304 + c * 48;
  for (int d = 0; d < 48; d++) Arow[d] = v[d] * inv;
}

// ---------------- outT[g][h*48+c] = sum_d attn[c][d] V[d][n] ---------------
// grid: x = n-tiles(49), y = bh(256). MFMA: M=n(64), N=c(48), K=d(48 pad 64).
__global__ __launch_bounds__(256) void k_attn_v(const u16* __restrict__ QKV,
                                                const float* __restrict__ attn,
                                                u16* __restrict__ outT) {
  int bh = blockIdx.y, b = bh >> 3, h = bh & 7;
  int n0 = blockIdx.x * 64;
  const u16* V = QKV + (size_t)(2 * D_ + h * C_) * BN_ + b * N_;
  __shared__ u16 Vt[64][64];   // [n_local][d], zero-padded d 48..63
  __shared__ u16 Aw[48][64];   // attn [c][d] bf16, zero-padded d 48..63
  int t = threadIdx.x;
  for (int i = t; i < 64 * 64 * 2 / 16; i += 256) ((int4*)Vt)[i] = int4{0, 0, 0, 0};
  for (int i = t; i < 48 * 64 * 2 / 16; i += 256) ((int4*)Aw)[i] = int4{0, 0, 0, 0};
  __syncthreads();
  for (int idx = t; idx < 768; idx += 256) {
    int d = idx >> 4, c4 = (idx & 15) * 4;
    ushort4 v = *(const ushort4*)(V + (size_t)d * BN_ + n0 + c4);
    Vt[c4 + 0][d] = v.x; Vt[c4 + 1][d] = v.y;
    Vt[c4 + 2][d] = v.z; Vt[c4 + 3][d] = v.w;
  }
  for (int i = t; i < 2304; i += 256) {
    int c = i / 48, d = i - c * 48;
    Aw[c][d] = f2b(attn[(size_t)bh * 2304 + i]);
  }
  __syncthreads();
  int wid = t >> 6, lane = t & 63;
  int r = lane & 15, quad = lane >> 4, q8 = quad * 8;
  floatx4 acc[3] = {};
  for (int ks = 0; ks < 2; ks++) {
    bf16x8 a = *(const bf16x8*)(&Vt[wid * 16 + r][ks * 32 + q8]);
    for (int nt = 0; nt < 3; nt++) {
      bf16x8 bb = *(const bf16x8*)(&Aw[nt * 16 + r][ks * 32 + q8]);
      acc[nt] = __builtin_amdgcn_mfma_f32_16x16x32_bf16(a, bb, acc[nt], 0, 0, 0);
    }
  }
  u16* Ob = outT + (size_t)(b * N_) * D_;
  for (int nt = 0; nt < 3; nt++)
    for (int j = 0; j < 4; j++) {
      int n = n0 + wid * 16 + quad * 4 + j;
      int e = h * C_ + nt * 16 + r;
      Ob[(size_t)n * D_ + e] = f2b(acc[nt][j]);
    }
}

// ---------------- proj: Y[g][f] = sum_e OT[g][e] P[f][e] + bias[f] ---------
// XCD swizzle: 2352 = 8 * 294; each XCD gets 98 g-tiles x 3 f-tiles so the
// OT g-tile is reused from that XCD's L2 across the 3 f-tiles.
__global__ __launch_bounds__(256) void k_gemm_proj(const u16* __restrict__ OT,
                                                   const u16* __restrict__ P,
                                                   const float* __restrict__ bias,
                                                   float* __restrict__ Y) {
  const int K = D_;
  int id = blockIdx.x;
  int work = (id & 7) * 294 + (id >> 3);
  int n0 = (work % 3) * 128;   // f
  int m0 = (work / 3) * 128;   // g
  __shared__ u16 As[128][32];
  __shared__ u16 Bs[128][32];
  int t = threadIdx.x, wid = t >> 6, lane = t & 63;
  int srow = wid * 32 + (lane >> 2);
  int scol = (lane & 3) * 8;
  int wm = (wid & 1) * 64, wn = (wid >> 1) * 64;
  int r = lane & 15, quad = lane >> 4, q8 = quad * 8;

  const u16* gA = OT + (size_t)(m0 + srow) * K + scol;
  const u16* gB = P + (size_t)(n0 + srow) * K + scol;
  u16* lA0 = &As[wid * 32][0];
  u16* lA1 = &As[wid * 32 + 16][0];
  u16* lB0 = &Bs[wid * 32][0];
  u16* lB1 = &Bs[wid * 32 + 16][0];

  floatx4 acc[4][4] = {};
  for (int k0 = 0; k0 < K; k0 += 32) {
    gload16(gA + k0, lA0);
    gload16(gA + k0 + 16 * K, lA1);
    gload16(gB + k0, lB0);
    gload16(gB + k0 + 16 * K, lB1);
    __syncthreads();
    bf16x8 af[4], bf[4];
    for (int i = 0; i < 4; i++) af[i] = *(const bf16x8*)(&As[wm + i * 16 + r][q8]);
    for (int j = 0; j < 4; j++) bf[j] = *(const bf16x8*)(&Bs[wn + j * 16 + r][q8]);
    for (int i = 0; i < 4; i++)
      for (int j = 0; j < 4; j++)
        acc[i][j] = __builtin_amdgcn_mfma_f32_16x16x32_bf16(af[i], bf[j], acc[i][j], 0, 0, 0);
    __syncthreads();
  }
  for (int i = 0; i < 4; i++)
    for (int j = 0; j < 4; j++) {
      int cc = n0 + wn + j * 16 + r;
      float bv = bias[cc];
      for (int v = 0; v < 4; v++) {
        int rr = m0 + wm + i * 16 + quad * 4 + v;
        Y[(size_t)rr * D_ + cc] = acc[i][j][v] + bv;
      }
    }
}

extern "C" void kernel_launch(void* const* d_in, const int* in_sizes, int n_in,
                              void* d_out, int out_size, void* d_ws, size_t ws_size,
                              hipStream_t stream) {
  const float* x      = (const float*)d_in[0];   // 32*3136*384
  const float* qkv_w  = (const float*)d_in[1];   // 1152*384
  const float* temp   = (const float*)d_in[2];   // 8
  const float* proj_w = (const float*)d_in[3];   // 384*384
  const float* proj_b = (const float*)d_in[4];   // 384
  float* out = (float*)d_out;

  // workspace layout (bytes), total ~311.8 MB
  char* ws = (char*)d_ws;
  u16*   qkv      = (u16*)(ws);                  // 231,211,008  [e][g] bf16
  u16*   xbf      = (u16*)(ws + 231211008);      //  77,070,336  x bf16 [g][d]
  // after gemm_qkv, xbf region is reused: S_part (16.5MB) + ssq_part (688KB),
  // then both are dead after softmax and the region becomes outT [g][e].
  float* S_part   = (float*)(ws + 231211008);    //  16,515,072  [7][bh][48][48]
  float* ssq_part = (float*)(ws + 247726080);    //     688,128  [7][2][bh][48]
  u16*   outT     = xbf;
  u16*   wbf      = (u16*)(ws + 308281344);      //     884,736
  u16*   pwbf     = (u16*)(ws + 309166080);      //     294,912
  float* attn     = (float*)(ws + 309460992);    //   2,359,296

  k_cvt<<<38535168 / 4 / 256, 256, 0, stream>>>(x, xbf, 38535168 / 4);
  k_cvt<<<442368 / 4 / 256, 256, 0, stream>>>(qkv_w, wbf, 442368 / 4);
  k_cvt<<<147456 / 4 / 256, 256, 0, stream>>>(proj_w, pwbf, 147456 / 4);

  k_gemm_qkv<<<7056, 256, 0, stream>>>(wbf, xbf, qkv);
  k_attn_s<<<dim3(256, 7), 256, 0, stream>>>(qkv, S_part, ssq_part);
  k_softmax<<<256, 64, 0, stream>>>(S_part, ssq_part, temp, attn);
  k_attn_v<<<dim3(49, 256), 256, 0, stream>>>(qkv, attn, outT);
  k_gemm_proj<<<2352, 256, 0, stream>>>(outT, pwbf, proj_b, out);
}